// Round 7
// baseline (240.350 us; speedup 1.0000x reference)
//
#include <hip/hip_runtime.h>
#include <vector>
#include <cmath>
#include <cstdint>

// ---------------------------------------------------------------------------
// Sparse Clebsch-Gordan tensor product, LMAX=5, TAUS=16, BATCH=256.
//
// R7: reuse-inverted structure. Block = (batch, (l1,l2) case). Each thread
// owns (i, jp), loads F1[.,i] / F2[.,2jp..2jp+1] into REGISTERS once, then
// produces ALL valid (l,m) output fragments for that case: up to 36
// independent float4 stores with nothing but register FMAs between them.
// All structural metadata is constexpr (21-way template switch); CG coeffs
// staged to LDS once per block, read at compile-time offsets (broadcast).
// ---------------------------------------------------------------------------

#define LMAXQ 5

typedef float f32x4 __attribute__((ext_vector_type(4)));

// ----------------------- constexpr enumeration (int only) ------------------

__host__ __device__ constexpr int cumt(int l) {          // complex-slot offset of segment l
    int s = 0; for (int a = 0; a < l; ++a) s += 16 * (2 * a + 1); return s;
}
__host__ __device__ constexpr bool validlp(int l, int l1, int l2) {
    int d = l1 > l2 ? l1 - l2 : l2 - l1;
    return l >= d && l <= l1 + l2;
}
__host__ __device__ constexpr int npairs(int l) {
    int n = 0;
    for (int a = 0; a <= LMAXQ; ++a) for (int b = a; b <= LMAXQ; ++b)
        if (validlp(l, a, b)) ++n;
    return n;
}
__host__ __device__ constexpr int pair_rank(int l, int l1, int l2) {
    int n = 0;
    for (int a = 0; a <= LMAXQ; ++a) for (int b = a; b <= LMAXQ; ++b)
        if (validlp(l, a, b)) { if (a == l1 && b == l2) return n; ++n; }
    return -1;
}
__host__ __device__ constexpr int jid_base(int l) {
    int s = 0; for (int a = 0; a < l; ++a) s += (2 * a + 1) * npairs(a); return s;
}
__host__ __device__ constexpr int lo_term(int l1, int l2, int m) {
    return (-l1 > m - l2) ? -l1 : m - l2;
}
__host__ __device__ constexpr int cnt_terms(int l1, int l2, int m) {
    int lo = lo_term(l1, l2, m);
    int hi = (l1 < m + l2) ? l1 : m + l2;
    return hi - lo + 1;
}
__host__ __device__ constexpr int case_id(int l1, int l2) {
    int n = 0;
    for (int a = 0; a <= LMAXQ; ++a) for (int b = a; b <= LMAXQ; ++b) {
        if (a == l1 && b == l2) return n; ++n;
    }
    return -1;
}
__host__ __device__ constexpr int case_len(int l1, int l2) {
    int s = 0;
    for (int l = 0; l <= LMAXQ; ++l) {
        if (!validlp(l, l1, l2)) continue;
        for (int mi = 0; mi <= 2 * l; ++mi) s += cnt_terms(l1, l2, mi - l);
    }
    return s;
}
__host__ __device__ constexpr int case_base(int l1, int l2) {
    int s = 0;
    for (int a = 0; a <= LMAXQ; ++a) for (int b = a; b <= LMAXQ; ++b) {
        if (a == l1 && b == l2) return s;
        s += case_len(a, b);
    }
    return -1;
}

constexpr int NCASES   = 21;
constexpr int F_ROWS   = 576;       // complex slots per batch
constexpr int NBATCH   = 256;
constexpr int F4_PER_B = 457 * 128; // float4 per batch
constexpr int MAXLEN   = 336;       // >= case_len(5,5)=326

// ------------------------- host-side CG coefficients -----------------------

static double factd(int n) { double r = 1.0; for (int i = 2; i <= n; ++i) r *= (double)i; return r; }

static double cg_coef(int j1, int m1, int j2, int m2, int j, int m) {
    if (m1 + m2 != m) return 0.0;
    double pref = std::sqrt((2.0 * j + 1.0) * factd(j + j1 - j2) * factd(j - j1 + j2) *
                            factd(j1 + j2 - j) / factd(j1 + j2 + j + 1));
    pref *= std::sqrt(factd(j + m) * factd(j - m) * factd(j1 - m1) * factd(j1 + m1) *
                      factd(j2 - m2) * factd(j2 + m2));
    int kmin = std::max(0, std::max(j2 - j - m1, j1 + m2 - j));
    int kmax = std::min(j1 + j2 - j, std::min(j1 - m1, j2 + m2));
    double s = 0.0;
    for (int k = kmin; k <= kmax; ++k) {
        s += ((k & 1) ? -1.0 : 1.0) /
             (factd(k) * factd(j1 + j2 - j - k) * factd(j1 - m1 - k) * factd(j2 + m2 - k) *
              factd(j - j2 + m1 + k) * factd(j - j1 - m2 + k));
    }
    return pref * s;
}

// coeff array in case-major order, mirroring the constexpr layout exactly
static const std::vector<float>& get_coeffs() {
    static std::vector<float> v = []() {
        std::vector<float> v;
        for (int a = 0; a <= LMAXQ; ++a) for (int b = a; b <= LMAXQ; ++b)
            for (int l = 0; l <= LMAXQ; ++l) {
                if (!validlp(l, a, b)) continue;
                for (int mi = 0; mi <= 2 * l; ++mi) {
                    int m  = mi - l;
                    int lo = lo_term(a, b, m), n = cnt_terms(a, b, m);
                    for (int k = 0; k < n; ++k) {
                        int m1 = lo + k;
                        v.push_back((float)cg_coef(a, m1, b, m - m1, l, m));
                    }
                }
            }
        return v;
    }();
    return v;
}

// --------------------------------- kernel ----------------------------------

template<int L1, int L2>
__device__ __forceinline__ void run_case(
    const float2* __restrict__ Fb, f32x4* __restrict__ outb,
    const float* __restrict__ gcoef, float* __restrict__ sc,
    int i, int jp)
{
    constexpr int LEN  = case_len(L1, L2);
    constexpr int BASE = case_base(L1, L2);

    // stage this case's coefficients to LDS (once per block)
    for (int t = threadIdx.x; t < LEN; t += 128) sc[t] = gcoef[BASE + t];
    __syncthreads();

    // operand fragments -> registers (all indices compile-time)
    float2 f1[2 * L1 + 1];
    f32x4  f2[2 * L2 + 1];
    #pragma unroll
    for (int x = 0; x <= 2 * L1; ++x)
        f1[x] = Fb[cumt(L1) + x * 16 + i];
    #pragma unroll
    for (int y = 0; y <= 2 * L2; ++y)
        f2[y] = *(const f32x4*)(Fb + cumt(L2) + y * 16 + 2 * jp);

    const int lane_off = i * 8 + jp;   // float4 offset inside a fragment

    int co = 0;                        // folds to constants after unroll
    #pragma unroll
    for (int l = 0; l <= LMAXQ; ++l) {
        if (!validlp(l, L1, L2)) continue;
        #pragma unroll
        for (int mi = 0; mi <= 2 * l; ++mi) {
            const int m  = mi - l;
            const int lo = lo_term(L1, L2, m);
            const int n  = cnt_terms(L1, L2, m);
            float aR0 = 0.f, aI0 = 0.f, aR1 = 0.f, aI1 = 0.f;
            #pragma unroll
            for (int k = 0; k < n; ++k) {
                const float  c = sc[co + k];
                const float2 a = f1[lo + k + L1];
                const f32x4  v = f2[m - lo - k + L2];
                aR0 = fmaf(c, a.x * v.x - a.y * v.y, aR0);
                aI0 = fmaf(c, a.x * v.y + a.y * v.x, aI0);
                aR1 = fmaf(c, a.x * v.z - a.y * v.w, aR1);
                aI1 = fmaf(c, a.x * v.w + a.y * v.z, aI1);
            }
            co += n;
            const int jid = jid_base(l) + mi * npairs(l) + pair_rank(l, L1, L2);
            f32x4 val; val.x = aR0; val.y = aI0; val.z = aR1; val.w = aI1;
            outb[jid * 128 + lane_off] = val;
        }
    }
}

__global__ __launch_bounds__(128, 4) void cg_tp_kernel(
    const float2* __restrict__ Fs, f32x4* __restrict__ out,
    const float* __restrict__ gcoef)
{
    __shared__ float sc[MAXLEN];
    const int c     = blockIdx.x % NCASES;     // case interleaved for balance
    const int batch = blockIdx.x / NCASES;

    const float2* __restrict__ Fb   = Fs + (size_t)batch * F_ROWS;
    f32x4* __restrict__        outb = out + (size_t)batch * F4_PER_B;

    const int i  = threadIdx.x >> 3;   // tau1 0..15
    const int jp = threadIdx.x & 7;    // tau2 pair 0..7

    switch (c) {
#define RC(A, B) case case_id(A, B): run_case<A, B>(Fb, outb, gcoef, sc, i, jp); break;
        RC(0,0) RC(0,1) RC(0,2) RC(0,3) RC(0,4) RC(0,5)
        RC(1,1) RC(1,2) RC(1,3) RC(1,4) RC(1,5)
        RC(2,2) RC(2,3) RC(2,4) RC(2,5)
        RC(3,3) RC(3,4) RC(3,5)
        RC(4,4) RC(4,5)
        RC(5,5)
#undef RC
    }
}

// ------------------------------ entry point --------------------------------

extern "C" void kernel_launch(void* const* d_in, const int* in_sizes, int n_in,
                              void* d_out, int out_size, void* d_ws, size_t ws_size,
                              hipStream_t stream) {
    const std::vector<float>& coeffs = get_coeffs();

    float* d_coeffs = (float*)d_ws;
    hipMemcpyAsync(d_coeffs, coeffs.data(), coeffs.size() * sizeof(float),
                   hipMemcpyHostToDevice, stream);

    const float2* Fs  = (const float2*)d_in[0];
    f32x4*        out = (f32x4*)d_out;

    const int nblocks = NBATCH * NCASES;
    cg_tp_kernel<<<nblocks, 128, 0, stream>>>(Fs, out, d_coeffs);
}

// Round 8
// 97.505 us; speedup vs baseline: 2.4650x; 2.4650x over previous
//
#include <hip/hip_runtime.h>
#include <vector>
#include <cmath>
#include <cstdint>

// ---------------------------------------------------------------------------
// Sparse Clebsch-Gordan tensor product, LMAX=5, TAUS=16, BATCH=256.
//
// R8 = R5's proven store schedule (dense grid-stride sweep over the output,
// regular f32x4 stores -> WRITE_SIZE exactly 233,984 KB, no RMW) + latency
// fixes on the compute side:
//   - jobs (457 x int4) and coeffs (2211 f32) staged to LDS once per block
//   - wave-uniform decode forced scalar via readfirstlane (scalar branch)
//   - switch(count) -> 11 fully-unrolled k-loop bodies: all 2*cnt F-loads
//     issue back-to-back (deep MLP), then a pure register-FMA tail.
// ---------------------------------------------------------------------------

#define LMAXV 5
#define NTAU 16

static const int CUMT[7] = {0, 16, 64, 144, 256, 400, 576};
constexpr int F_ROWS  = 576;                      // complex rows per batch
constexpr int NBATCH  = 256;
constexpr uint32_t F4_PER_BATCH = 457u * 128u;    // 58,496 float4 per batch
constexpr uint32_t NTOT = F4_PER_BATCH * NBATCH;  // 14,974,976 float4
constexpr int GRID = 2048, BLK = 256;
constexpr int NJOBS = 457, NCOEF = 2211;

typedef float f32x4 __attribute__((ext_vector_type(4)));

// ------------------------- host-side CG table build ------------------------

static double factd(int n) { double r = 1.0; for (int i = 2; i <= n; ++i) r *= (double)i; return r; }

static double cg_coef(int j1, int m1, int j2, int m2, int j, int m) {
    if (m1 + m2 != m) return 0.0;
    double pref = std::sqrt((2.0 * j + 1.0) * factd(j + j1 - j2) * factd(j - j1 + j2) *
                            factd(j1 + j2 - j) / factd(j1 + j2 + j + 1));
    pref *= std::sqrt(factd(j + m) * factd(j - m) * factd(j1 - m1) * factd(j1 + m1) *
                      factd(j2 - m2) * factd(j2 + m2));
    int kmin = std::max(0, std::max(j2 - j - m1, j1 + m2 - j));
    int kmax = std::min(j1 + j2 - j, std::min(j1 - m1, j2 + m2));
    double s = 0.0;
    for (int k = kmin; k <= kmax; ++k) {
        s += ((k & 1) ? -1.0 : 1.0) /
             (factd(k) * factd(j1 + j2 - j - k) * factd(j1 - m1 - k) * factd(j2 + m2 - k) *
              factd(j - j2 + m1 + k) * factd(j - j1 - m2 + k));
    }
    return pref * s;
}

struct Tables { std::vector<int4> jobs; std::vector<float> coeffs; };

static const Tables& get_tables() {
    static Tables t = []() {
        Tables t;
        for (int l = 0; l <= LMAXV; ++l) {
            for (int m_idx = 0; m_idx < 2 * l + 1; ++m_idx) {
                int m = m_idx - l;
                for (int l1 = 0; l1 <= LMAXV; ++l1) {
                    for (int l2 = l1; l2 <= LMAXV; ++l2) {
                        if (!(std::abs(l1 - l2) <= l && l <= l1 + l2)) continue;
                        int lo = std::max(-l1, m - l2), hi = std::min(l1, m + l2);
                        int4 jb;
                        jb.x = CUMT[l1] + (lo + l1) * NTAU;      // F1 row at m1=lo
                        jb.y = CUMT[l2] + (m - lo + l2) * NTAU;  // F2 row at m2=m-lo
                        jb.z = hi - lo + 1;                      // count <= 11
                        jb.w = (int)t.coeffs.size();             // coeff offset
                        for (int m1 = lo; m1 <= hi; ++m1)
                            t.coeffs.push_back((float)cg_coef(l1, m1, l2, m - m1, l, m));
                        t.jobs.push_back(jb);
                    }
                }
            }
        }
        return t;
    }();
    return t;
}

// --------------------------------- kernel ----------------------------------

#define KBODY(N)                                                              \
    {                                                                         \
        float2 a[N]; f32x4 v[N]; float cc[N];                                 \
        _Pragma("unroll")                                                     \
        for (int k = 0; k < N; ++k) {                                         \
            a[k]  = pa[k * NTAU];                                             \
            v[k]  = *(const f32x4*)(pv - k * NTAU);                           \
            cc[k] = sc[coff + k];                                             \
        }                                                                     \
        _Pragma("unroll")                                                     \
        for (int k = 0; k < N; ++k) {                                         \
            aR0 = fmaf(cc[k], a[k].x * v[k].x - a[k].y * v[k].y, aR0);        \
            aI0 = fmaf(cc[k], a[k].x * v[k].y + a[k].y * v[k].x, aI0);        \
            aR1 = fmaf(cc[k], a[k].x * v[k].z - a[k].y * v[k].w, aR1);        \
            aI1 = fmaf(cc[k], a[k].x * v[k].w + a[k].y * v[k].z, aI1);        \
        }                                                                     \
    }

__global__ __launch_bounds__(256) void cg_tp_kernel(
    const float2* __restrict__ Fs, f32x4* __restrict__ out,
    const int4* __restrict__ jobs, const float* __restrict__ coeffs)
{
    __shared__ int4  sj[NJOBS];
    __shared__ float sc[NCOEF];
    for (int t = threadIdx.x; t < NJOBS; t += BLK) sj[t] = jobs[t];
    for (int t = threadIdx.x; t < NCOEF; t += BLK) sc[t] = coeffs[t];
    __syncthreads();

    const uint32_t lane = threadIdx.x & 63u;
    const uint32_t G    = (uint32_t)GRID * BLK;

    for (uint32_t g = (uint32_t)blockIdx.x * BLK + threadIdx.x; g < NTOT; g += G) {
        // wave-uniform scalar decode: g of lane 0 is a multiple of 64
        const uint32_t gs    = __builtin_amdgcn_readfirstlane(g) & ~63u;
        const uint32_t batch = gs / F4_PER_BATCH;
        const uint32_t rem0  = gs - batch * F4_PER_BATCH;
        const uint32_t jid   = rem0 >> 7;
        const uint32_t half  = (rem0 >> 6) & 1u;

        const uint32_t w  = half * 64u + lane;
        const uint32_t i  = w >> 3;          // tau1 0..15
        const uint32_t jp = w & 7u;          // tau2 pair 0..7

        const int4 jbv = sj[jid];            // LDS broadcast read
        const int x_base = __builtin_amdgcn_readfirstlane(jbv.x);
        const int y_base = __builtin_amdgcn_readfirstlane(jbv.y);
        const int cnt    = __builtin_amdgcn_readfirstlane(jbv.z);
        const int coff   = __builtin_amdgcn_readfirstlane(jbv.w);

        const float2* __restrict__ F  = Fs + (size_t)batch * F_ROWS;
        const float2* __restrict__ pa = F + x_base + i;        // +k*16 per term
        const float2* __restrict__ pv = F + y_base + 2 * jp;   // -k*16 per term

        float aR0 = 0.f, aI0 = 0.f, aR1 = 0.f, aI1 = 0.f;
        switch (cnt) {
            case 1:  KBODY(1)  break;
            case 2:  KBODY(2)  break;
            case 3:  KBODY(3)  break;
            case 4:  KBODY(4)  break;
            case 5:  KBODY(5)  break;
            case 6:  KBODY(6)  break;
            case 7:  KBODY(7)  break;
            case 8:  KBODY(8)  break;
            case 9:  KBODY(9)  break;
            case 10: KBODY(10) break;
            default: KBODY(11) break;
        }

        f32x4 val; val.x = aR0; val.y = aI0; val.z = aR1; val.w = aI1;
        out[g] = val;                        // dense in-order sweep (R5 schedule)
    }
}

// ------------------------------ entry point --------------------------------

extern "C" void kernel_launch(void* const* d_in, const int* in_sizes, int n_in,
                              void* d_out, int out_size, void* d_ws, size_t ws_size,
                              hipStream_t stream) {
    const Tables& t = get_tables();

    char*  ws       = (char*)d_ws;
    int4*  d_jobs   = (int4*)ws;
    size_t jbytes   = t.jobs.size() * sizeof(int4);
    size_t coff     = (jbytes + 255) & ~(size_t)255;
    float* d_coeffs = (float*)(ws + coff);

    hipMemcpyAsync(d_jobs, t.jobs.data(), jbytes, hipMemcpyHostToDevice, stream);
    hipMemcpyAsync(d_coeffs, t.coeffs.data(), t.coeffs.size() * sizeof(float),
                   hipMemcpyHostToDevice, stream);

    const float2* Fs  = (const float2*)d_in[0];
    f32x4*        out = (f32x4*)d_out;

    cg_tp_kernel<<<GRID, BLK, 0, stream>>>(Fs, out, d_jobs, d_coeffs);
}

// Round 9
// 64.862 us; speedup vs baseline: 3.7056x; 1.5033x over previous
//
#include <hip/hip_runtime.h>
#include <vector>
#include <cmath>
#include <cstdint>

// ---------------------------------------------------------------------------
// Sparse Clebsch-Gordan tensor product, LMAX=5, TAUS=16, BATCH=256.
//
// R9: pipe separation. Block = (batch, chunk-of-~57-jobs). The batch's F is
// staged into LDS in two TRANSPOSED layouts so each thread's k-terms are
// contiguous LDS elements (fusable ds_read2, conflict-free bank mapping):
//   F1T[i][x]  as 8B elems :  a[k] = F1T[cumt(l1) + i*(2l1+1) + x0 + k]
//   F2T[jp][y] as 16B elems:  v[k] = F2T[cumt(l2)/2 + jp*(2l2+1) + y0 - k]
// Coeffs (2211 f32) + chunk jobs also in LDS. The k-loop touches ONLY LDS;
// the VMEM pipe carries nothing but the coalesced f32x4 output stream
// (fillBuffer-style, which measures 6.8+ TB/s on this buffer).
// ---------------------------------------------------------------------------

#define LMAXV 5
#define NTAU 16

static const int CUMT[7] = {0, 16, 64, 144, 256, 400, 576};
__host__ __device__ constexpr int cumt_ce(int l) {
    int s = 0; for (int a = 0; a < l; ++a) s += 16 * (2 * a + 1); return s;
}

constexpr int F_ROWS   = 576;            // complex rows per batch
constexpr int NBATCH   = 256;
constexpr int F4_PER_B = 457 * 128;      // float4 per batch
constexpr int BLK      = 256;
constexpr int NCHUNK   = 8;              // 457 = 7*57 + 58
constexpr int NJOBS    = 457;
constexpr int NCOEF    = 2211;
constexpr int MAXJC    = 58;

typedef float f32x4 __attribute__((ext_vector_type(4)));

// ------------------------- host-side CG table build ------------------------

static double factd(int n) { double r = 1.0; for (int i = 2; i <= n; ++i) r *= (double)i; return r; }

static double cg_coef(int j1, int m1, int j2, int m2, int j, int m) {
    if (m1 + m2 != m) return 0.0;
    double pref = std::sqrt((2.0 * j + 1.0) * factd(j + j1 - j2) * factd(j - j1 + j2) *
                            factd(j1 + j2 - j) / factd(j1 + j2 + j + 1));
    pref *= std::sqrt(factd(j + m) * factd(j - m) * factd(j1 - m1) * factd(j1 + m1) *
                      factd(j2 - m2) * factd(j2 + m2));
    int kmin = std::max(0, std::max(j2 - j - m1, j1 + m2 - j));
    int kmax = std::min(j1 + j2 - j, std::min(j1 - m1, j2 + m2));
    double s = 0.0;
    for (int k = kmin; k <= kmax; ++k) {
        s += ((k & 1) ? -1.0 : 1.0) /
             (factd(k) * factd(j1 + j2 - j - k) * factd(j1 - m1 - k) * factd(j2 + m2 - k) *
              factd(j - j2 + m1 + k) * factd(j - j1 - m2 + k));
    }
    return pref * s;
}

struct Tables { std::vector<int4> jobs; std::vector<float> coeffs; };

static const Tables& get_tables() {
    static Tables t = []() {
        Tables t;
        for (int l = 0; l <= LMAXV; ++l) {
            for (int m_idx = 0; m_idx < 2 * l + 1; ++m_idx) {
                int m = m_idx - l;
                for (int l1 = 0; l1 <= LMAXV; ++l1) {
                    for (int l2 = l1; l2 <= LMAXV; ++l2) {
                        if (!(std::abs(l1 - l2) <= l && l <= l1 + l2)) continue;
                        int lo = std::max(-l1, m - l2), hi = std::min(l1, m + l2);
                        int4 jb;
                        // a_base0 | stride1<<16 : elem idx into F1T (8B elems)
                        jb.x = (CUMT[l1] + lo + l1) | ((2 * l1 + 1) << 16);
                        // b_base0 | stride2<<16 : elem idx into F2T (16B elems)
                        jb.y = (CUMT[l2] / 2 + m - lo + l2) | ((2 * l2 + 1) << 16);
                        jb.z = hi - lo + 1;                      // count <= 11
                        jb.w = (int)t.coeffs.size();             // coeff offset
                        for (int m1 = lo; m1 <= hi; ++m1)
                            t.coeffs.push_back((float)cg_coef(l1, m1, l2, m - m1, l, m));
                        t.jobs.push_back(jb);
                    }
                }
            }
        }
        return t;
    }();
    return t;
}

// --------------------------------- kernel ----------------------------------

#define KBODY(N)                                                              \
    {                                                                         \
        float2 a[N]; f32x4 v[N]; float cc[N];                                 \
        _Pragma("unroll")                                                     \
        for (int k = 0; k < N; ++k) {                                         \
            a[k]  = pa[k];                                                    \
            v[k]  = pv[-k];                                                   \
            cc[k] = sC[coff + k];                                             \
        }                                                                     \
        _Pragma("unroll")                                                     \
        for (int k = 0; k < N; ++k) {                                         \
            aR0 = fmaf(cc[k], a[k].x * v[k].x - a[k].y * v[k].y, aR0);        \
            aI0 = fmaf(cc[k], a[k].x * v[k].y + a[k].y * v[k].x, aI0);        \
            aR1 = fmaf(cc[k], a[k].x * v[k].z - a[k].y * v[k].w, aR1);        \
            aI1 = fmaf(cc[k], a[k].x * v[k].w + a[k].y * v[k].z, aI1);        \
        }                                                                     \
    }

__global__ __launch_bounds__(256) void cg_tp_kernel(
    const float2* __restrict__ Fs, f32x4* __restrict__ out,
    const int4* __restrict__ jobs, const float* __restrict__ coeffs)
{
    __shared__ float2 sF1[F_ROWS];       // [i][x] per l-seg, 8B elems
    __shared__ f32x4  sF2[F_ROWS / 2];   // [jp][y] per l-seg, 16B elems
    __shared__ float  sC[NCOEF];
    __shared__ int4   sJ[MAXJC];

    const int tid   = threadIdx.x;
    const int batch = blockIdx.x >> 3;          // batch-major grid
    const int chunk = blockIdx.x & (NCHUNK - 1);
    const int jbase = chunk * 57;
    const int jcnt  = (chunk == NCHUNK - 1) ? 58 : 57;

    const float2* __restrict__ Fb = Fs + (size_t)batch * F_ROWS;

    // ---- stage: transposed F, coeffs, chunk jobs ----
#define STAGE_L(L)                                                            \
    {                                                                         \
        constexpr int base = cumt_ce(L);                                      \
        constexpr int w    = 2 * (L) + 1;                                     \
        for (int t = tid; t < 16 * w; t += BLK) {                             \
            int i = t / w, x = t - i * w;                                     \
            sF1[base + t] = Fb[base + x * 16 + i];                            \
        }                                                                     \
        for (int t = tid; t < 8 * w; t += BLK) {                              \
            int jp = t / w, y = t - jp * w;                                   \
            sF2[base / 2 + t] = *(const f32x4*)&Fb[base + y * 16 + 2 * jp];   \
        }                                                                     \
    }
    STAGE_L(0) STAGE_L(1) STAGE_L(2) STAGE_L(3) STAGE_L(4) STAGE_L(5)
#undef STAGE_L
    for (int t = tid; t < NCOEF; t += BLK) sC[t] = coeffs[t];
    for (int t = tid; t < jcnt;  t += BLK) sJ[t] = jobs[jbase + t];
    __syncthreads();

    const int half = tid >> 7;          // this half-block's job parity
    const int t128 = tid & 127;
    const int i    = t128 >> 3;         // tau1 0..15
    const int jp   = t128 & 7;          // tau2 pair 0..7

    f32x4* __restrict__ outb = out + (size_t)batch * F4_PER_B + (size_t)jbase * 128 + t128;

    for (int jj = half; jj < jcnt; jj += 2) {
        const int4 jbv = sJ[jj];
        const int ax   = __builtin_amdgcn_readfirstlane(jbv.x);
        const int by   = __builtin_amdgcn_readfirstlane(jbv.y);
        const int cnt  = __builtin_amdgcn_readfirstlane(jbv.z);
        const int coff = __builtin_amdgcn_readfirstlane(jbv.w);

        const float2* __restrict__ pa = sF1 + (ax & 0xffff) + i  * (ax >> 16);
        const f32x4*  __restrict__ pv = sF2 + (by & 0xffff) + jp * (by >> 16);

        float aR0 = 0.f, aI0 = 0.f, aR1 = 0.f, aI1 = 0.f;
        switch (cnt) {
            case 1:  KBODY(1)  break;
            case 2:  KBODY(2)  break;
            case 3:  KBODY(3)  break;
            case 4:  KBODY(4)  break;
            case 5:  KBODY(5)  break;
            case 6:  KBODY(6)  break;
            case 7:  KBODY(7)  break;
            case 8:  KBODY(8)  break;
            case 9:  KBODY(9)  break;
            case 10: KBODY(10) break;
            default: KBODY(11) break;
        }

        f32x4 val; val.x = aR0; val.y = aI0; val.z = aR1; val.w = aI1;
        outb[(size_t)jj * 128] = val;   // contiguous per job, coalesced
    }
}

// ------------------------------ entry point --------------------------------

extern "C" void kernel_launch(void* const* d_in, const int* in_sizes, int n_in,
                              void* d_out, int out_size, void* d_ws, size_t ws_size,
                              hipStream_t stream) {
    const Tables& t = get_tables();

    char*  ws       = (char*)d_ws;
    int4*  d_jobs   = (int4*)ws;
    size_t jbytes   = t.jobs.size() * sizeof(int4);
    size_t coff     = (jbytes + 255) & ~(size_t)255;
    float* d_coeffs = (float*)(ws + coff);

    hipMemcpyAsync(d_jobs, t.jobs.data(), jbytes, hipMemcpyHostToDevice, stream);
    hipMemcpyAsync(d_coeffs, t.coeffs.data(), t.coeffs.size() * sizeof(float),
                   hipMemcpyHostToDevice, stream);

    const float2* Fs  = (const float2*)d_in[0];
    f32x4*        out = (f32x4*)d_out;

    cg_tp_kernel<<<NBATCH * NCHUNK, BLK, 0, stream>>>(Fs, out, d_jobs, d_coeffs);
}

// Round 10
// 57.573 us; speedup vs baseline: 4.1747x; 1.1266x over previous
//
#include <hip/hip_runtime.h>
#include <vector>
#include <cmath>
#include <cstdint>

// ---------------------------------------------------------------------------
// Sparse Clebsch-Gordan tensor product, LMAX=5, TAUS=16, BATCH=256.
//
// R10 = R9's pipe separation (all operand reads in LDS, VMEM = pure store
// stream) + 2x2 micro-tile per thread:
//   thread (ip,jp) owns i in {2ip,2ip+1} x j in {2jp,2jp+1} -> per term BOTH
//   operand reads are ds_read_b128 (a = F1[x, 2ip..2ip+1], v = F2[y,
//   2jp..2jp+1]) and ONE wave covers a whole 16x16 job tile (was 2).
//   LDS cycles per output halve: ~28 us of LDS pipe vs ~36 us store drain.
// The natural complex layout read as f32x4 serves both operands -> a single
// untransposed 4.6 KB LDS copy of the batch's F. Bank-conflict-free by
// construction (addr = C + ip / D + jp -> banks 4*{0..7}, 8-way broadcast).
// Store schedule unchanged from R9 (batch-major chunks, contiguous 2 KB per
// job, WRITE_SIZE exact, no RMW).
// ---------------------------------------------------------------------------

#define LMAXV 5
#define NTAU 16

static const int CUMT[7] = {0, 16, 64, 144, 256, 400, 576};

constexpr int F_ROWS   = 576;            // complex rows per batch
constexpr int F4_ROWS  = 288;            // as f32x4 (i-pairs)
constexpr int NBATCH   = 256;
constexpr int F4_PER_B = 457 * 128;      // float4 per batch
constexpr int BLK      = 256;
constexpr int NCHUNK   = 8;              // 457 = 7*57 + 58
constexpr int NCOEF    = 2211;
constexpr int MAXJC    = 58;

typedef float f32x4 __attribute__((ext_vector_type(4)));

// ------------------------- host-side CG table build ------------------------

static double factd(int n) { double r = 1.0; for (int i = 2; i <= n; ++i) r *= (double)i; return r; }

static double cg_coef(int j1, int m1, int j2, int m2, int j, int m) {
    if (m1 + m2 != m) return 0.0;
    double pref = std::sqrt((2.0 * j + 1.0) * factd(j + j1 - j2) * factd(j - j1 + j2) *
                            factd(j1 + j2 - j) / factd(j1 + j2 + j + 1));
    pref *= std::sqrt(factd(j + m) * factd(j - m) * factd(j1 - m1) * factd(j1 + m1) *
                      factd(j2 - m2) * factd(j2 + m2));
    int kmin = std::max(0, std::max(j2 - j - m1, j1 + m2 - j));
    int kmax = std::min(j1 + j2 - j, std::min(j1 - m1, j2 + m2));
    double s = 0.0;
    for (int k = kmin; k <= kmax; ++k) {
        s += ((k & 1) ? -1.0 : 1.0) /
             (factd(k) * factd(j1 + j2 - j - k) * factd(j1 - m1 - k) * factd(j2 + m2 - k) *
              factd(j - j2 + m1 + k) * factd(j - j1 - m2 + k));
    }
    return pref * s;
}

struct Tables { std::vector<int4> jobs; std::vector<float> coeffs; };

static const Tables& get_tables() {
    static Tables t = []() {
        Tables t;
        for (int l = 0; l <= LMAXV; ++l) {
            for (int m_idx = 0; m_idx < 2 * l + 1; ++m_idx) {
                int m = m_idx - l;
                for (int l1 = 0; l1 <= LMAXV; ++l1) {
                    for (int l2 = l1; l2 <= LMAXV; ++l2) {
                        if (!(std::abs(l1 - l2) <= l && l <= l1 + l2)) continue;
                        int lo = std::max(-l1, m - l2), hi = std::min(l1, m + l2);
                        int4 jb;
                        // byte offset into sF (f32x4 elems, 16B each) of term k=0
                        // a: f32x4 idx = cumt/2 + x*8 + ip  (x = lo+l1, +k per term)
                        jb.x = (CUMT[l1] / 2 + (lo + l1) * 8) * 16;
                        // v: f32x4 idx = cumt2/2 + y*8 + jp (y = m-lo+l2, -k per term)
                        jb.y = (CUMT[l2] / 2 + (m - lo + l2) * 8) * 16;
                        jb.z = hi - lo + 1;                      // count <= 11
                        jb.w = (int)t.coeffs.size();             // coeff offset
                        for (int m1 = lo; m1 <= hi; ++m1)
                            t.coeffs.push_back((float)cg_coef(l1, m1, l2, m - m1, l, m));
                        t.jobs.push_back(jb);
                    }
                }
            }
        }
        return t;
    }();
    return t;
}

// --------------------------------- kernel ----------------------------------

#define KBODY(N)                                                              \
    {                                                                         \
        f32x4 a[N], v[N]; float cc[N];                                        \
        _Pragma("unroll")                                                     \
        for (int k = 0; k < N; ++k) {                                         \
            a[k]  = *(const f32x4*)(sFb + ax + k * 128);                      \
            v[k]  = *(const f32x4*)(sFb + vy - k * 128);                      \
            cc[k] = sC[coff + k];                                             \
        }                                                                     \
        _Pragma("unroll")                                                     \
        for (int k = 0; k < N; ++k) {                                         \
            r00 = fmaf(cc[k], a[k].x * v[k].x - a[k].y * v[k].y, r00);        \
            i00 = fmaf(cc[k], a[k].x * v[k].y + a[k].y * v[k].x, i00);        \
            r01 = fmaf(cc[k], a[k].x * v[k].z - a[k].y * v[k].w, r01);        \
            i01 = fmaf(cc[k], a[k].x * v[k].w + a[k].y * v[k].z, i01);        \
            r10 = fmaf(cc[k], a[k].z * v[k].x - a[k].w * v[k].y, r10);        \
            i10 = fmaf(cc[k], a[k].z * v[k].y + a[k].w * v[k].x, i10);        \
            r11 = fmaf(cc[k], a[k].z * v[k].z - a[k].w * v[k].w, r11);        \
            i11 = fmaf(cc[k], a[k].z * v[k].w + a[k].w * v[k].z, i11);        \
        }                                                                     \
    }

__global__ __launch_bounds__(256) void cg_tp_kernel(
    const f32x4* __restrict__ Fs, f32x4* __restrict__ out,
    const int4* __restrict__ jobs, const float* __restrict__ coeffs)
{
    __shared__ f32x4 sF[F4_ROWS];        // batch's F, natural layout
    __shared__ float sC[NCOEF];
    __shared__ int4  sJ[MAXJC];

    const int tid   = threadIdx.x;
    const int batch = blockIdx.x >> 3;          // batch-major grid
    const int chunk = blockIdx.x & (NCHUNK - 1);
    const int jbase = chunk * 57;
    const int jcnt  = (chunk == NCHUNK - 1) ? 58 : 57;

    // ---- stage: F (4.6 KB direct copy), coeffs, chunk jobs ----
    {
        const f32x4* __restrict__ Fb4 = Fs + (size_t)batch * F4_ROWS;
        for (int t = tid; t < F4_ROWS; t += BLK) sF[t] = Fb4[t];
        for (int t = tid; t < NCOEF;   t += BLK) sC[t] = coeffs[t];
        for (int t = tid; t < jcnt;    t += BLK) sJ[t] = jobs[jbase + t];
    }
    __syncthreads();

    const int wv   = tid >> 6;          // wave 0..3: handles jobs wv, wv+4, ...
    const int lane = tid & 63;
    const int ip   = lane >> 3;         // i-pair 0..7
    const int jp   = lane & 7;          // j-pair 0..7
    const char* __restrict__ sFb = (const char*)sF;

    f32x4* __restrict__ outb =
        out + (size_t)batch * F4_PER_B + (size_t)jbase * 128;

    for (int jj = wv; jj < jcnt; jj += 4) {
        const int4 jbv = sJ[jj];
        const int ax   = __builtin_amdgcn_readfirstlane(jbv.x) + ip * 16;
        const int vy   = __builtin_amdgcn_readfirstlane(jbv.y) + jp * 16;
        const int cnt  = __builtin_amdgcn_readfirstlane(jbv.z);
        const int coff = __builtin_amdgcn_readfirstlane(jbv.w);

        float r00 = 0.f, i00 = 0.f, r01 = 0.f, i01 = 0.f;
        float r10 = 0.f, i10 = 0.f, r11 = 0.f, i11 = 0.f;

        switch (cnt) {
            case 1:  KBODY(1)  break;
            case 2:  KBODY(2)  break;
            case 3:  KBODY(3)  break;
            case 4:  KBODY(4)  break;
            case 5:  KBODY(5)  break;
            case 6:  KBODY(6)  break;
            case 7:  KBODY(7)  break;
            case 8:  KBODY(8)  break;
            case 9:  KBODY(9)  break;
            case 10: KBODY(10) break;
            default: KBODY(11) break;
        }

        // rows i=2ip and 2ip+1, columns 2jp..2jp+1
        f32x4 s0; s0.x = r00; s0.y = i00; s0.z = r01; s0.w = i01;
        f32x4 s1; s1.x = r10; s1.y = i10; s1.z = r11; s1.w = i11;
        f32x4* __restrict__ po = outb + (size_t)jj * 128 + ip * 16 + jp;
        po[0] = s0;          // i = 2ip
        po[8] = s1;          // i = 2ip+1
    }
}

// ------------------------------ entry point --------------------------------

extern "C" void kernel_launch(void* const* d_in, const int* in_sizes, int n_in,
                              void* d_out, int out_size, void* d_ws, size_t ws_size,
                              hipStream_t stream) {
    const Tables& t = get_tables();

    char*  ws       = (char*)d_ws;
    int4*  d_jobs   = (int4*)ws;
    size_t jbytes   = t.jobs.size() * sizeof(int4);
    size_t coff     = (jbytes + 255) & ~(size_t)255;
    float* d_coeffs = (float*)(ws + coff);

    hipMemcpyAsync(d_jobs, t.jobs.data(), jbytes, hipMemcpyHostToDevice, stream);
    hipMemcpyAsync(d_coeffs, t.coeffs.data(), t.coeffs.size() * sizeof(float),
                   hipMemcpyHostToDevice, stream);

    const f32x4* Fs  = (const f32x4*)d_in[0];
    f32x4*       out = (f32x4*)d_out;

    cg_tp_kernel<<<NBATCH * NCHUNK, BLK, 0, stream>>>(Fs, out, d_jobs, d_coeffs);
}